// Round 7
// baseline (259.813 us; speedup 1.0000x reference)
//
#include <hip/hip_runtime.h>
#include <math.h>

#define G 64
#define GV (G*G*G)      // 262144
#define NB 8

typedef unsigned short u16;
typedef unsigned int u32;
typedef unsigned long long U64;
typedef __bf16 bf16x8 __attribute__((ext_vector_type(8)));
typedef float f32x4 __attribute__((ext_vector_type(4)));

union BF8 { u16 s[8]; bf16x8 v; };

__device__ __forceinline__ float bf2f(u16 h) {
    union { u32 u; float f; } c; c.u = ((u32)h) << 16; return c.f;
}
__device__ __forceinline__ u16 f2bf(float f) {
    union { float f; u32 u; } c; c.f = f;
    u32 u = c.u;
    return (u16)((u + 0x7fffu + ((u >> 16) & 1u)) >> 16);   // RNE
}
__device__ __forceinline__ u32 cvt_pk_bf16(float lo, float hi) {
    u32 r;
    asm volatile("v_cvt_pk_bf16_f32 %0, %1, %2" : "=v"(r) : "v"(lo), "v"(hi));
    return r;
}

#define YSTRIDE 76   // u32 per voxel row: yh at [0..35], yl at [40..75]

// ---------------------------------------------------------------------------
// convA via MFMA, split-precision (R4-proven math & LDS exchange layout),
// restructured as a 1-deep pipeline:
//   iter t: GEMM1+relu+pack(tile t) -> Ybuf[t&1]
//           GEMM2+store(tile t-1)   <- Ybuf[(t-1)&1]   (no drain fence)
// Per-wave double-buffered Y; weights staged via LDS then that region is
// reused for the Y buffers (union, 2nd barrier). LDS total ~43.7 KB.
// Block: 256 thr = 4 waves, box 4z x 4y x 64x; 16 tiles of 16 voxels/wave.
// ---------------------------------------------------------------------------
__global__ __launch_bounds__(256) void convA_mfma_kernel(
    const float* __restrict__ bnd,
    const float* __restrict__ w1, const float* __restrict__ b1,
    const float* __restrict__ w2,
    u16* __restrict__ zbuf)
{
    int b = blockIdx.y;
    const float* bd = bnd + (size_t)b * GV;
    u16* zb = zbuf + (size_t)b * (27 * (size_t)GV);

    __shared__ __align__(16) u16 halo[2378];     // 6*6*66 + zero slot
    __shared__ __align__(16) u32 shpool[9728];   // weights (3520 f32) -> Y dbuf

    int tid = threadIdx.x;
    int z0 = (blockIdx.x >> 4) * 4, y0 = (blockIdx.x & 15) * 4;

    // ---- coalesced weight stage into shpool-as-float ----
    {
        float* ldsW = (float*)shpool;
        for (int i = tid; i < 3520; i += 256) {
            float v;
            if (i < 1728)      v = w1[i];
            else if (i < 3456) v = w2[i - 1728];
            else               v = b1[i - 3456];
            ldsW[i] = v;
        }
    }

    // ---- halo fill (bf16 bit patterns 0x3F80 / 0) ----
    for (int i = tid; i < 2378; i += 256) {
        u16 hval = 0;
        if (i < 2376) {
            int hz = i / 396, rem = i - hz * 396;
            int hy = rem / 66, hx = rem - hy * 66;
            int gz = z0 + hz - 1, gy = y0 + hy - 1, gx = hx - 1;
            if (((unsigned)gz < (unsigned)G) & ((unsigned)gy < (unsigned)G) &
                ((unsigned)gx < (unsigned)G)) {
                float f = bd[(gz << 12) + (gy << 6) + gx];
                hval = (f > 0.5f) ? (u16)0x3F80 : (u16)0;
            }
        }
        halo[i] = hval;
    }

    __syncthreads();

    int wv = tid >> 6, lane = tid & 63;
    int g = lane >> 4, lr = lane & 15;

    // ---- fragment build from LDS, hi/lo split (identical values to R4) ----
    const float* ldsW = (const float*)shpool;
    BF8 w1Ah[4], w1Al[4];           // GEMM1 A: 4 c-tiles, K=27 pad 32
#pragma unroll
    for (int m = 0; m < 4; m++) {
        int c = 16 * m + lr;
#pragma unroll
        for (int j = 0; j < 8; j++) {
            int kk = 8 * g + j;
            float w = (kk < 27) ? ldsW[c * 27 + kk] : 0.0f;
            u16 hi = f2bf(w);
            w1Ah[m].s[j] = hi;
            w1Al[m].s[j] = f2bf(w - bf2f(hi));
        }
    }
    BF8 w2Ah[2][2], w2Al[2][2];     // GEMM2 A: 2 t-tiles x 2 K-steps
#pragma unroll
    for (int m2 = 0; m2 < 2; m2++) {
        int t = 16 * m2 + lr;
#pragma unroll
        for (int ks = 0; ks < 2; ks++)
#pragma unroll
            for (int j = 0; j < 8; j++) {
                int ch = 32 * ks + 8 * g + j;
                float w = (t < 27) ? ldsW[1728 + ch * 27 + t] : 0.0f;
                u16 hi = f2bf(w);
                w2Ah[m2][ks].s[j] = hi;
                w2Al[m2][ks].s[j] = f2bf(w - bf2f(hi));
            }
    }
    float bias[4][4];               // b1 for D rows c = 16m+4g+r (exact f32)
#pragma unroll
    for (int m = 0; m < 4; m++)
#pragma unroll
        for (int r = 0; r < 4; r++) bias[m][r] = ldsW[3456 + 16 * m + 4 * g + r];

    // ---- per-lane tap offsets for the X^T gather ----
    int tapoff[8]; bool tapok[8];
#pragma unroll
    for (int j = 0; j < 8; j++) {
        int kk = 8 * g + j;
        int kc = kk < 27 ? kk : 0;
        int dz = kc / 9, ry = kc - dz * 9;
        int dy = ry / 3, dx = ry - dy * 3;
        tapoff[j] = dz * 396 + dy * 66 + dx;
        tapok[j] = (kk < 27);
    }

    __syncthreads();    // weights region now dead -> reuse as Y buffers

    u32* myY0 = shpool + wv * 2432;         // 2 buffers x 16 x 76 u32
    u32* myY1 = myY0 + 1216;

    // GEMM1 + relu + hi/lo pack -> DST (R4-proven layout)
    auto gemm1pack = [&](int IT, u32* DST) {
        int li = IT >> 2, xt = IT & 3;
        int l = wv * 4 + li;
        int lineoff = ((l >> 2) * 6 + (l & 3)) * 66 + lr + xt * 16;

        BF8 xB;
#pragma unroll
        for (int j = 0; j < 8; j++) {
            int a = lineoff + tapoff[j];
            a = tapok[j] ? a : 2376;      // zero slot
            xB.s[j] = halo[a];
        }

        f32x4 yac[4];
#pragma unroll
        for (int m = 0; m < 4; m++) {
            f32x4 c0;
            c0[0] = bias[m][0]; c0[1] = bias[m][1];
            c0[2] = bias[m][2]; c0[3] = bias[m][3];
            c0 = __builtin_amdgcn_mfma_f32_16x16x32_bf16(
                w1Al[m].v, xB.v, c0, 0, 0, 0);
            yac[m] = __builtin_amdgcn_mfma_f32_16x16x32_bf16(
                w1Ah[m].v, xB.v, c0, 0, 0, 0);
        }

#pragma unroll
        for (int m = 0; m < 4; m++) {
            float a0 = fmaxf(yac[m][0], 0.f), a1 = fmaxf(yac[m][1], 0.f);
            float a2 = fmaxf(yac[m][2], 0.f), a3 = fmaxf(yac[m][3], 0.f);
            u32 h01 = cvt_pk_bf16(a0, a1);
            u32 h23 = cvt_pk_bf16(a2, a3);
            u32 l01 = cvt_pk_bf16(a0 - bf2f((u16)(h01 & 0xffffu)),
                                  a1 - bf2f((u16)(h01 >> 16)));
            u32 l23 = cvt_pk_bf16(a2 - bf2f((u16)(h23 & 0xffffu)),
                                  a3 - bf2f((u16)(h23 >> 16)));
            int c0u = 8 * m + 2 * g;            // (16m+4g)>>1
            DST[lr * YSTRIDE + c0u]          = h01;
            DST[lr * YSTRIDE + c0u + 1]      = h23;
            DST[lr * YSTRIDE + 40 + c0u]     = l01;
            DST[lr * YSTRIDE + 40 + c0u + 1] = l23;
        }
    };

    // GEMM2 + store <- SRC (R4-proven layout: u32 offset 16ks+4g, +40 lo)
    auto gemm2store = [&](int IT, const u32* SRC) {
        int li = IT >> 2, xt = IT & 3;
        int l = wv * 4 + li;
        int vbase = ((z0 + (l >> 2)) << 12) + ((y0 + (l & 3)) << 6) + xt * 16;

        f32x4 zac[2];
        zac[0] = f32x4{0.f, 0.f, 0.f, 0.f};
        zac[1] = f32x4{0.f, 0.f, 0.f, 0.f};
#pragma unroll
        for (int ks = 0; ks < 2; ks++) {
            bf16x8 yBh = *(const bf16x8*)&SRC[lr * YSTRIDE + 16 * ks + 4 * g];
            bf16x8 yBl = *(const bf16x8*)&SRC[lr * YSTRIDE + 40 + 16 * ks + 4 * g];
#pragma unroll
            for (int m2 = 0; m2 < 2; m2++) {
                zac[m2] = __builtin_amdgcn_mfma_f32_16x16x32_bf16(
                    w2Al[m2][ks].v, yBh, zac[m2], 0, 0, 0);
                zac[m2] = __builtin_amdgcn_mfma_f32_16x16x32_bf16(
                    w2Ah[m2][ks].v, yBl, zac[m2], 0, 0, 0);
                zac[m2] = __builtin_amdgcn_mfma_f32_16x16x32_bf16(
                    w2Ah[m2][ks].v, yBh, zac[m2], 0, 0, 0);
            }
        }

        int vg = vbase + lr;
#pragma unroll
        for (int m2 = 0; m2 < 2; m2++)
#pragma unroll
            for (int r = 0; r < 4; r++) {
                int t = 16 * m2 + 4 * g + r;
                if (t < 27)
                    zb[(size_t)t * GV + vg] = f2bf(zac[m2][r]);
            }
    };

    // ---- 1-deep pipeline over the 16 tiles ----
    gemm1pack(0, myY0);
    for (int it = 1; it < 16; ++it) {
        u32* cur  = (it & 1) ? myY1 : myY0;
        u32* prev = (it & 1) ? myY0 : myY1;
        gemm1pack(it, cur);
        asm volatile("" ::: "memory");   // order prev writes vs reads (compiler)
        gemm2store(it - 1, prev);
    }
    asm volatile("" ::: "memory");
    gemm2store(15, myY1);
}

// ---------------------------------------------------------------------------
// Kernel B: conv2 tap-stencil: x2(v) = relu(b2 + sum_t z_t(v + d_t))
// ---------------------------------------------------------------------------
__global__ __launch_bounds__(256) void convB_kernel(
    const u16* __restrict__ zbuf, size_t z_bs,
    float* __restrict__ xout, size_t x_bs,
    const float* __restrict__ b2)
{
    int b = blockIdx.y;
    const u16* zb = zbuf + (size_t)b * z_bs;
    float* xo = xout + (size_t)b * x_bs;

    int v  = blockIdx.x * 256 + threadIdx.x;
    int zc = v >> 12, yc = (v >> 6) & 63, xc = v & 63;
    float acc = b2[0];
#pragma unroll
    for (int dz = -1; dz <= 1; dz++)
#pragma unroll
    for (int dy = -1; dy <= 1; dy++)
#pragma unroll
    for (int dx = -1; dx <= 1; dx++) {
        int t = (dz + 1) * 9 + (dy + 1) * 3 + (dx + 1);
        int zz = zc + dz, yy = yc + dy, xx = xc + dx;
        bool ok = ((unsigned)zz < (unsigned)G) & ((unsigned)yy < (unsigned)G) &
                  ((unsigned)xx < (unsigned)G);
        if (ok) acc += bf2f(zb[(size_t)t * GV + (zz << 12) + (yy << 6) + xx]);
    }
    xo[v] = fmaxf(acc, 0.0f);
}

// ---------------------------------------------------------------------------
// fc1: block (jt, vc) handles 8 rows j0..j0+7 x 4096-v chunk, all 8 batches.
// ---------------------------------------------------------------------------
__global__ __launch_bounds__(256) void fc1_kernel(
    const float* __restrict__ W, const float* __restrict__ x,
    float* __restrict__ pacc)
{
    int jt = blockIdx.x;            // 0..31
    int vc = blockIdx.y;            // 0..63
    int tid = threadIdx.x;
    int j0 = jt * 8;
    size_t v0 = (size_t)vc * 4096;

    const float4* Wp[8];
#pragma unroll
    for (int jj = 0; jj < 8; jj++)
        Wp[jj] = reinterpret_cast<const float4*>(W + (size_t)(j0 + jj) * GV + v0);
    const float4* Xp[NB];
#pragma unroll
    for (int b = 0; b < NB; b++)
        Xp[b] = reinterpret_cast<const float4*>(x + (size_t)b * GV + v0);

    float acc[8][NB];
#pragma unroll
    for (int jj = 0; jj < 8; jj++)
#pragma unroll
        for (int b = 0; b < NB; b++) acc[jj][b] = 0.0f;

    for (int i = 0; i < 4; i++) {
        int e = i * 256 + tid;
        float4 wvv[8];
#pragma unroll
        for (int jj = 0; jj < 8; jj++) wvv[jj] = Wp[jj][e];
        float4 xv[NB];
#pragma unroll
        for (int b = 0; b < NB; b++) xv[b] = Xp[b][e];
#pragma unroll
        for (int b = 0; b < NB; b++) {
#pragma unroll
            for (int jj = 0; jj < 8; jj++) {
                acc[jj][b] = fmaf(wvv[jj].x, xv[b].x, acc[jj][b]);
                acc[jj][b] = fmaf(wvv[jj].y, xv[b].y, acc[jj][b]);
                acc[jj][b] = fmaf(wvv[jj].z, xv[b].z, acc[jj][b]);
                acc[jj][b] = fmaf(wvv[jj].w, xv[b].w, acc[jj][b]);
            }
        }
    }

    __shared__ float sacc[256][36];
    __shared__ float p2[8][40];
#pragma unroll
    for (int pass = 0; pass < 2; pass++) {
        if (pass > 0) __syncthreads();
        float4* row = reinterpret_cast<float4*>(&sacc[tid][0]);
#pragma unroll
        for (int jj = 0; jj < 4; jj++) {
            int js = pass * 4 + jj;
            row[jj * 2 + 0] = make_float4(acc[js][0], acc[js][1], acc[js][2], acc[js][3]);
            row[jj * 2 + 1] = make_float4(acc[js][4], acc[js][5], acc[js][6], acc[js][7]);
        }
        __syncthreads();
        {
            int o = tid & 31, gg = tid >> 5;
            float s = 0.0f;
#pragma unroll
            for (int k = 0; k < 32; k++) s += sacc[gg * 32 + k][o];
            p2[gg][o] = s;
        }
        __syncthreads();
        if (tid < 32) {
            float s = 0.0f;
#pragma unroll
            for (int gg = 0; gg < 8; gg++) s += p2[gg][tid];
            int jj = tid >> 3, b = tid & 7;
            pacc[((size_t)b * 64 + vc) * 256 + (j0 + pass * 4 + jj)] = s;
        }
    }
}

// ---------------------------------------------------------------------------
__global__ __launch_bounds__(256) void fc_final_kernel(
    const float* __restrict__ pacc, const float* __restrict__ fc1_b,
    const float* __restrict__ fc2_w, const float* __restrict__ fc2_b,
    float* __restrict__ prob)
{
    int j = threadIdx.x;
    float h[NB];
#pragma unroll
    for (int b = 0; b < NB; b++) h[b] = 0.0f;
    for (int c = 0; c < 64; c++) {
#pragma unroll
        for (int b = 0; b < NB; b++)
            h[b] += pacc[((size_t)b * 64 + c) * 256 + j];
    }
    float w2j = fc2_w[j];
    float contrib[NB];
#pragma unroll
    for (int b = 0; b < NB; b++)
        contrib[b] = fmaxf(h[b] + fc1_b[j], 0.0f) * w2j;

    int lane = j & 63, wid = j >> 6;
#pragma unroll
    for (int b = 0; b < NB; b++)
#pragma unroll
        for (int off = 32; off > 0; off >>= 1)
            contrib[b] += __shfl_down(contrib[b], off, 64);

    __shared__ float sred[4][NB];
    if (lane == 0) {
#pragma unroll
        for (int b = 0; b < NB; b++) sred[wid][b] = contrib[b];
    }
    __syncthreads();
    if (j < NB) {
        float t = sred[0][j] + sred[1][j] + sred[2][j] + sred[3][j] + fc2_b[0];
        prob[j] = 100.0f / (1.0f + expf(-t));
    }
}

// ---------------------------------------------------------------------------
__global__ __launch_bounds__(256) void zero_pts_kernel(float4* __restrict__ out)
{
    out[blockIdx.x * 256 + threadIdx.x] = make_float4(0.f, 0.f, 0.f, 0.f);
}

#define BPB 32

__global__ __launch_bounds__(256) void topk1_kernel(
    const float* __restrict__ bnd, const float* __restrict__ noise,
    U64* __restrict__ cand)
{
    int blk = blockIdx.x;
    int b   = blockIdx.y;
    int tid = threadIdx.x;
    int vbase = blk * (GV / BPB);
    const float* bd = bnd + (size_t)b * GV + vbase;
    const float* nz = noise + (size_t)b * GV + vbase;

    U64 top[10];
#pragma unroll
    for (int k = 0; k < 10; k++) top[k] = 0ull;

    for (int i = 0; i < (GV / BPB) / 256; i++) {
        int e = i * 256 + tid;
        float bv = bd[e];
        float s  = nz[e];
        U64 p = (bv > 0.5f) ? 0ull
              : ((((U64)__float_as_uint(s)) << 32) | (unsigned)(vbase + e));
        if (p > top[9]) {
#pragma unroll
            for (int k = 0; k < 10; k++) {
                U64 mx = p > top[k] ? p : top[k];
                U64 mn = p > top[k] ? top[k] : p;
                top[k] = mx; p = mn;
            }
        }
    }

    __shared__ U64 lcand[256 * 10];
    __shared__ U64 rv[256];
    __shared__ int rp[256];
#pragma unroll
    for (int k = 0; k < 10; k++) lcand[tid * 10 + k] = top[k];
    __syncthreads();

    for (int pass = 0; pass < 10; pass++) {
        U64 bv = 0; int bp = 0;
        for (int i = tid; i < 2560; i += 256) {
            U64 xv = lcand[i];
            if (xv > bv) { bv = xv; bp = i; }
        }
        rv[tid] = bv; rp[tid] = bp;
        __syncthreads();
        for (int off = 128; off > 0; off >>= 1) {
            if (tid < off) {
                if (rv[tid + off] > rv[tid]) { rv[tid] = rv[tid + off]; rp[tid] = rp[tid + off]; }
            }
            __syncthreads();
        }
        if (tid == 0) {
            cand[((size_t)b * BPB + blk) * 10 + pass] = rv[0];
            lcand[rp[0]] = 0ull;
        }
        __syncthreads();
    }
}

__global__ __launch_bounds__(256) void topk2_kernel(
    const U64* __restrict__ cand, float* __restrict__ pts)
{
    int b = blockIdx.x, tid = threadIdx.x;
    __shared__ U64 lc[BPB * 10];
    __shared__ U64 rv[256];
    __shared__ int rp[256];
    __shared__ int widx[10];
    for (int i = tid; i < BPB * 10; i += 256) lc[i] = cand[(size_t)b * BPB * 10 + i];
    __syncthreads();

    for (int pass = 0; pass < 10; pass++) {
        U64 bv = 0; int bp = 0;
        for (int i = tid; i < BPB * 10; i += 256) {
            U64 xv = lc[i];
            if (xv > bv) { bv = xv; bp = i; }
        }
        rv[tid] = bv; rp[tid] = bp;
        __syncthreads();
        for (int off = 128; off > 0; off >>= 1) {
            if (tid < off) {
                if (rv[tid + off] > rv[tid]) { rv[tid] = rv[tid + off]; rp[tid] = rp[tid + off]; }
            }
            __syncthreads();
        }
        if (tid == 0) { widx[pass] = (int)(rv[0] & 0xffffffffu); lc[rp[0]] = 0ull; }
        __syncthreads();
    }
    if (tid < 10) pts[(size_t)b * GV + widx[tid]] = 1.0f;
}

// ---------------------------------------------------------------------------
extern "C" void kernel_launch(void* const* d_in, const int* in_sizes, int n_in,
                              void* d_out, int out_size, void* d_ws, size_t ws_size,
                              hipStream_t stream)
{
    const float* bnd   = (const float*)d_in[0];
    const float* w1    = (const float*)d_in[1];
    const float* b1    = (const float*)d_in[2];
    const float* w2    = (const float*)d_in[3];
    const float* b2    = (const float*)d_in[4];
    const float* fw1   = (const float*)d_in[5];
    const float* fb1   = (const float*)d_in[6];
    const float* fw2   = (const float*)d_in[7];
    const float* fb2   = (const float*)d_in[8];
    const float* noise = (const float*)d_in[9];

    float* out = (float*)d_out;
    char* ws = (char*)d_ws;

    const size_t xbuf_off = 0;                                 // 8 MB
    const size_t pacc_off = xbuf_off + (size_t)NB * GV * 4;    // 512 KB
    const size_t cand_off = pacc_off + (size_t)NB * 64 * 256 * 4;
    const size_t zbuf_off = cand_off + (size_t)NB * BPB * 10 * 8;

    float* xbuf = (float*)(ws + xbuf_off);
    float* pacc = (float*)(ws + pacc_off);
    U64*   cand = (U64*)(ws + cand_off);
    u16*   zbuf = (u16*)(ws + zbuf_off);                       // 8 x 13.5 MB

    dim3 gA(256, NB);       // (4z x 4y) boxes x 8 batches
    convA_mfma_kernel<<<gA, 256, 0, stream>>>(bnd, w1, b1, w2, zbuf);

    dim3 gB(GV / 256, NB);
    convB_kernel<<<gB, 256, 0, stream>>>(zbuf, (size_t)27 * GV, xbuf, (size_t)GV, b2);

    dim3 gfc(32, 64);
    fc1_kernel<<<gfc, 256, 0, stream>>>(fw1, xbuf, pacc);
    fc_final_kernel<<<1, 256, 0, stream>>>(pacc, fb1, fw2, fb2, out + (size_t)NB * GV);

    zero_pts_kernel<<<(NB * GV / 4) / 256, 256, 0, stream>>>((float4*)out);
    dim3 gt(BPB, NB);
    topk1_kernel<<<gt, 256, 0, stream>>>(bnd, noise, cand);
    topk2_kernel<<<NB, 256, 0, stream>>>(cand, out);
}

// Round 9
// 228.153 us; speedup vs baseline: 1.1388x; 1.1388x over previous
//
#include <hip/hip_runtime.h>
#include <math.h>

#define G 64
#define GV (G*G*G)      // 262144
#define NB 8

typedef unsigned short u16;
typedef unsigned int u32;
typedef unsigned long long U64;
typedef __bf16 bf16x8 __attribute__((ext_vector_type(8)));
typedef float f32x4 __attribute__((ext_vector_type(4)));

union BF8 { u16 s[8]; bf16x8 v; };

__device__ __forceinline__ float bf2f(u16 h) {
    union { u32 u; float f; } c; c.u = ((u32)h) << 16; return c.f;
}
__device__ __forceinline__ u16 f2bf(float f) {
    union { float f; u32 u; } c; c.f = f;
    u32 u = c.u;
    return (u16)((u + 0x7fffu + ((u >> 16) & 1u)) >> 16);   // RNE
}
__device__ __forceinline__ u32 cvt_pk_bf16(float lo, float hi) {
    u32 r;
    asm volatile("v_cvt_pk_bf16_f32 %0, %1, %2" : "=v"(r) : "v"(lo), "v"(hi));
    return r;
}

#define YSTRIDE 36   // u32 per voxel row (hi-only Y); b128-aligned, 2-way banks

// ---------------------------------------------------------------------------
// convA via MFMA:
//   GEMM1: Y^T[64c x 16v] = (W1h+W1l)[64c x 32k] @ X^T[32k x 16v]  (+bias C)
//          -> relu -> bf16 (hi only; prob error budget ~0.2 vs threshold 1.02)
//   exchange through per-wave LDS tile, 4 x ds_write_b64 / 2 x ds_read_b128
//   GEMM2: Z^T[32t x 16v] = (W2h+W2l) @ Yh      -> z stored bf16
// 1-deep pipeline (GEMM2 of tile t-1 after GEMM1 of tile t), per-wave dbuf.
// Block: 256 thr = 4 waves, box 4z x 4y x 64x; 16 tiles of 16 voxels/wave.
// ---------------------------------------------------------------------------
__global__ __launch_bounds__(256) void convA_mfma_kernel(
    const float* __restrict__ bnd,
    const float* __restrict__ w1, const float* __restrict__ b1,
    const float* __restrict__ w2,
    u16* __restrict__ zbuf)
{
    int b = blockIdx.y;
    const float* bd = bnd + (size_t)b * GV;
    u16* zb = zbuf + (size_t)b * (27 * (size_t)GV);

    __shared__ __align__(16) u16 halo[2378];     // 6*6*66 + zero slot
    __shared__ __align__(16) u32 shpool[4608];   // weights stage -> Y dbufs

    int tid = threadIdx.x;
    int z0 = (blockIdx.x >> 4) * 4, y0 = (blockIdx.x & 15) * 4;

    // ---- coalesced weight stage into shpool-as-float ----
    {
        float* ldsW = (float*)shpool;
        for (int i = tid; i < 3520; i += 256) {
            float v;
            if (i < 1728)      v = w1[i];
            else if (i < 3456) v = w2[i - 1728];
            else               v = b1[i - 3456];
            ldsW[i] = v;
        }
    }

    // ---- halo fill (bf16 bit patterns 0x3F80 / 0) ----
    for (int i = tid; i < 2378; i += 256) {
        u16 hval = 0;
        if (i < 2376) {
            int hz = i / 396, rem = i - hz * 396;
            int hy = rem / 66, hx = rem - hy * 66;
            int gz = z0 + hz - 1, gy = y0 + hy - 1, gx = hx - 1;
            if (((unsigned)gz < (unsigned)G) & ((unsigned)gy < (unsigned)G) &
                ((unsigned)gx < (unsigned)G)) {
                float f = bd[(gz << 12) + (gy << 6) + gx];
                hval = (f > 0.5f) ? (u16)0x3F80 : (u16)0;
            }
        }
        halo[i] = hval;
    }

    __syncthreads();

    int wv = tid >> 6, lane = tid & 63;
    int g = lane >> 4, lr = lane & 15;

    // ---- fragment build from LDS, hi/lo split weights ----
    const float* ldsW = (const float*)shpool;
    BF8 w1Ah[4], w1Al[4];           // GEMM1 A: 4 c-tiles, K=27 pad 32
#pragma unroll
    for (int m = 0; m < 4; m++) {
        int c = 16 * m + lr;
#pragma unroll
        for (int j = 0; j < 8; j++) {
            int kk = 8 * g + j;
            float w = (kk < 27) ? ldsW[c * 27 + kk] : 0.0f;
            u16 hi = f2bf(w);
            w1Ah[m].s[j] = hi;
            w1Al[m].s[j] = f2bf(w - bf2f(hi));
        }
    }
    BF8 w2Ah[2][2], w2Al[2][2];     // GEMM2 A: 2 t-tiles x 2 K-steps
#pragma unroll
    for (int m2 = 0; m2 < 2; m2++) {
        int t = 16 * m2 + lr;
#pragma unroll
        for (int ks = 0; ks < 2; ks++)
#pragma unroll
            for (int j = 0; j < 8; j++) {
                int ch = 32 * ks + 8 * g + j;
                float w = (t < 27) ? ldsW[1728 + ch * 27 + t] : 0.0f;
                u16 hi = f2bf(w);
                w2Ah[m2][ks].s[j] = hi;
                w2Al[m2][ks].s[j] = f2bf(w - bf2f(hi));
            }
    }
    float bias[4][4];               // b1 for D rows c = 16m+4g+r (exact f32)
#pragma unroll
    for (int m = 0; m < 4; m++)
#pragma unroll
        for (int r = 0; r < 4; r++) bias[m][r] = ldsW[3456 + 16 * m + 4 * g + r];

    // ---- per-lane tap offsets for the X^T gather ----
    int tapoff[8]; bool tapok[8];
#pragma unroll
    for (int j = 0; j < 8; j++) {
        int kk = 8 * g + j;
        int kc = kk < 27 ? kk : 0;
        int dz = kc / 9, ry = kc - dz * 9;
        int dy = ry / 3, dx = ry - dy * 3;
        tapoff[j] = dz * 396 + dy * 66 + dx;
        tapok[j] = (kk < 27);
    }

    __syncthreads();    // weights region now dead -> reuse as Y buffers

    u32* myY0 = shpool + wv * (2 * 16 * YSTRIDE);
    u32* myY1 = myY0 + 16 * YSTRIDE;

    // GEMM1 + relu + bf16 pack (hi only) -> DST via 4 x ds_write_b64
    auto gemm1pack = [&](int IT, u32* DST) {
        int li = IT >> 2, xt = IT & 3;
        int l = wv * 4 + li;
        int lineoff = ((l >> 2) * 6 + (l & 3)) * 66 + lr + xt * 16;

        BF8 xB;
#pragma unroll
        for (int j = 0; j < 8; j++) {
            int a = lineoff + tapoff[j];
            a = tapok[j] ? a : 2376;      // zero slot
            xB.s[j] = halo[a];
        }

        f32x4 yac[4];
#pragma unroll
        for (int m = 0; m < 4; m++) {
            f32x4 c0;
            c0[0] = bias[m][0]; c0[1] = bias[m][1];
            c0[2] = bias[m][2]; c0[3] = bias[m][3];
            c0 = __builtin_amdgcn_mfma_f32_16x16x32_bf16(
                w1Al[m].v, xB.v, c0, 0, 0, 0);
            yac[m] = __builtin_amdgcn_mfma_f32_16x16x32_bf16(
                w1Ah[m].v, xB.v, c0, 0, 0, 0);
        }

#pragma unroll
        for (int m = 0; m < 4; m++) {
            float a0 = fmaxf(yac[m][0], 0.f), a1 = fmaxf(yac[m][1], 0.f);
            float a2 = fmaxf(yac[m][2], 0.f), a3 = fmaxf(yac[m][3], 0.f);
            u32 h01 = cvt_pk_bf16(a0, a1);
            u32 h23 = cvt_pk_bf16(a2, a3);
            // pair (c0u, c0u+1), 8B-aligned -> single b64 write
            *(U64*)&DST[lr * YSTRIDE + 8 * m + 2 * g] =
                (U64)h01 | ((U64)h23 << 32);
        }
    };

    // GEMM2 + store <- SRC (b128 reads at u32 offset 16ks+4g)
    auto gemm2store = [&](int IT, const u32* SRC) {
        int li = IT >> 2, xt = IT & 3;
        int l = wv * 4 + li;
        int vbase = ((z0 + (l >> 2)) << 12) + ((y0 + (l & 3)) << 6) + xt * 16;

        f32x4 zac[2];
        zac[0] = f32x4{0.f, 0.f, 0.f, 0.f};
        zac[1] = f32x4{0.f, 0.f, 0.f, 0.f};
#pragma unroll
        for (int ks = 0; ks < 2; ks++) {
            bf16x8 yBh = *(const bf16x8*)&SRC[lr * YSTRIDE + 16 * ks + 4 * g];
#pragma unroll
            for (int m2 = 0; m2 < 2; m2++) {
                zac[m2] = __builtin_amdgcn_mfma_f32_16x16x32_bf16(
                    w2Al[m2][ks].v, yBh, zac[m2], 0, 0, 0);
                zac[m2] = __builtin_amdgcn_mfma_f32_16x16x32_bf16(
                    w2Ah[m2][ks].v, yBh, zac[m2], 0, 0, 0);
            }
        }

        int vg = vbase + lr;
#pragma unroll
        for (int m2 = 0; m2 < 2; m2++)
#pragma unroll
            for (int r = 0; r < 4; r++) {
                int t = 16 * m2 + 4 * g + r;
                if (t < 27)
                    zb[(size_t)t * GV + vg] = f2bf(zac[m2][r]);
            }
    };

    // ---- 1-deep pipeline over the 16 tiles ----
    gemm1pack(0, myY0);
    for (int it = 1; it < 16; ++it) {
        u32* cur  = (it & 1) ? myY1 : myY0;
        u32* prev = (it & 1) ? myY0 : myY1;
        gemm1pack(it, cur);
        asm volatile("" ::: "memory");
        gemm2store(it - 1, prev);
    }
    asm volatile("" ::: "memory");
    gemm2store(15, myY1);
}

// ---------------------------------------------------------------------------
// Kernel B: conv2 tap-stencil: x2(v) = relu(b2 + sum_t z_t(v + d_t))
// ---------------------------------------------------------------------------
__global__ __launch_bounds__(256) void convB_kernel(
    const u16* __restrict__ zbuf, size_t z_bs,
    float* __restrict__ xout, size_t x_bs,
    const float* __restrict__ b2)
{
    int b = blockIdx.y;
    const u16* zb = zbuf + (size_t)b * z_bs;
    float* xo = xout + (size_t)b * x_bs;

    int v  = blockIdx.x * 256 + threadIdx.x;
    int zc = v >> 12, yc = (v >> 6) & 63, xc = v & 63;
    float acc = b2[0];
#pragma unroll
    for (int dz = -1; dz <= 1; dz++)
#pragma unroll
    for (int dy = -1; dy <= 1; dy++)
#pragma unroll
    for (int dx = -1; dx <= 1; dx++) {
        int t = (dz + 1) * 9 + (dy + 1) * 3 + (dx + 1);
        int zz = zc + dz, yy = yc + dy, xx = xc + dx;
        bool ok = ((unsigned)zz < (unsigned)G) & ((unsigned)yy < (unsigned)G) &
                  ((unsigned)xx < (unsigned)G);
        if (ok) acc += bf2f(zb[(size_t)t * GV + (zz << 12) + (yy << 6) + xx]);
    }
    xo[v] = fmaxf(acc, 0.0f);
}

// ---------------------------------------------------------------------------
// fc1: block (jt, vc) handles 8 rows j0..j0+7 x 4096-v chunk, all 8 batches.
// W stream is use-once -> nontemporal loads via clang-native f32x4.
// ---------------------------------------------------------------------------
__global__ __launch_bounds__(256) void fc1_kernel(
    const float* __restrict__ W, const float* __restrict__ x,
    float* __restrict__ pacc)
{
    int jt = blockIdx.x;            // 0..31
    int vc = blockIdx.y;            // 0..63
    int tid = threadIdx.x;
    int j0 = jt * 8;
    size_t v0 = (size_t)vc * 4096;

    const f32x4* Wp[8];
#pragma unroll
    for (int jj = 0; jj < 8; jj++)
        Wp[jj] = reinterpret_cast<const f32x4*>(W + (size_t)(j0 + jj) * GV + v0);
    const f32x4* Xp[NB];
#pragma unroll
    for (int b = 0; b < NB; b++)
        Xp[b] = reinterpret_cast<const f32x4*>(x + (size_t)b * GV + v0);

    float acc[8][NB];
#pragma unroll
    for (int jj = 0; jj < 8; jj++)
#pragma unroll
        for (int b = 0; b < NB; b++) acc[jj][b] = 0.0f;

    for (int i = 0; i < 4; i++) {
        int e = i * 256 + tid;
        f32x4 wvv[8];
#pragma unroll
        for (int jj = 0; jj < 8; jj++)
            wvv[jj] = __builtin_nontemporal_load(&Wp[jj][e]);
        f32x4 xv[NB];
#pragma unroll
        for (int b = 0; b < NB; b++) xv[b] = Xp[b][e];
#pragma unroll
        for (int b = 0; b < NB; b++) {
#pragma unroll
            for (int jj = 0; jj < 8; jj++) {
                acc[jj][b] = fmaf(wvv[jj][0], xv[b][0], acc[jj][b]);
                acc[jj][b] = fmaf(wvv[jj][1], xv[b][1], acc[jj][b]);
                acc[jj][b] = fmaf(wvv[jj][2], xv[b][2], acc[jj][b]);
                acc[jj][b] = fmaf(wvv[jj][3], xv[b][3], acc[jj][b]);
            }
        }
    }

    __shared__ float sacc[256][36];
    __shared__ float p2[8][40];
#pragma unroll
    for (int pass = 0; pass < 2; pass++) {
        if (pass > 0) __syncthreads();
        float4* row = reinterpret_cast<float4*>(&sacc[tid][0]);
#pragma unroll
        for (int jj = 0; jj < 4; jj++) {
            int js = pass * 4 + jj;
            row[jj * 2 + 0] = make_float4(acc[js][0], acc[js][1], acc[js][2], acc[js][3]);
            row[jj * 2 + 1] = make_float4(acc[js][4], acc[js][5], acc[js][6], acc[js][7]);
        }
        __syncthreads();
        {
            int o = tid & 31, gg = tid >> 5;
            float s = 0.0f;
#pragma unroll
            for (int k = 0; k < 32; k++) s += sacc[gg * 32 + k][o];
            p2[gg][o] = s;
        }
        __syncthreads();
        if (tid < 32) {
            float s = 0.0f;
#pragma unroll
            for (int gg = 0; gg < 8; gg++) s += p2[gg][tid];
            int jj = tid >> 3, b = tid & 7;
            pacc[((size_t)b * 64 + vc) * 256 + (j0 + pass * 4 + jj)] = s;
        }
    }
}

// ---------------------------------------------------------------------------
__global__ __launch_bounds__(256) void fc_final_kernel(
    const float* __restrict__ pacc, const float* __restrict__ fc1_b,
    const float* __restrict__ fc2_w, const float* __restrict__ fc2_b,
    float* __restrict__ prob)
{
    int j = threadIdx.x;
    float h[NB];
#pragma unroll
    for (int b = 0; b < NB; b++) h[b] = 0.0f;
    for (int c = 0; c < 64; c++) {
#pragma unroll
        for (int b = 0; b < NB; b++)
            h[b] += pacc[((size_t)b * 64 + c) * 256 + j];
    }
    float w2j = fc2_w[j];
    float contrib[NB];
#pragma unroll
    for (int b = 0; b < NB; b++)
        contrib[b] = fmaxf(h[b] + fc1_b[j], 0.0f) * w2j;

    int lane = j & 63, wid = j >> 6;
#pragma unroll
    for (int b = 0; b < NB; b++)
#pragma unroll
        for (int off = 32; off > 0; off >>= 1)
            contrib[b] += __shfl_down(contrib[b], off, 64);

    __shared__ float sred[4][NB];
    if (lane == 0) {
#pragma unroll
        for (int b = 0; b < NB; b++) sred[wid][b] = contrib[b];
    }
    __syncthreads();
    if (j < NB) {
        float t = sred[0][j] + sred[1][j] + sred[2][j] + sred[3][j] + fc2_b[0];
        prob[j] = 100.0f / (1.0f + expf(-t));
    }
}

// ---------------------------------------------------------------------------
__global__ __launch_bounds__(256) void zero_pts_kernel(float4* __restrict__ out)
{
    out[blockIdx.x * 256 + threadIdx.x] = make_float4(0.f, 0.f, 0.f, 0.f);
}

#define BPB 32
#define IDXM 0x3FFFFu   // GV-1; key low bits = IDXM - idx (smallest idx wins ties)

__global__ __launch_bounds__(256) void topk1_kernel(
    const float* __restrict__ bnd, const float* __restrict__ noise,
    U64* __restrict__ cand)
{
    int blk = blockIdx.x;
    int b   = blockIdx.y;
    int tid = threadIdx.x;
    int vbase = blk * (GV / BPB);
    const float* bd = bnd + (size_t)b * GV + vbase;
    const float* nz = noise + (size_t)b * GV + vbase;

    U64 top[10];
#pragma unroll
    for (int k = 0; k < 10; k++) top[k] = 0ull;

    for (int i = 0; i < (GV / BPB) / 256; i++) {
        int e = i * 256 + tid;
        float bv = bd[e];
        float s  = nz[e];
        U64 p = (bv > 0.5f) ? 0ull
              : ((((U64)__float_as_uint(s)) << 32) |
                 (IDXM - (unsigned)(vbase + e)));
        if (p > top[9]) {
#pragma unroll
            for (int k = 0; k < 10; k++) {
                U64 mx = p > top[k] ? p : top[k];
                U64 mn = p > top[k] ? top[k] : p;
                top[k] = mx; p = mn;
            }
        }
    }

    __shared__ U64 lcand[256 * 10];
    __shared__ U64 rv[256];
    __shared__ int rp[256];
#pragma unroll
    for (int k = 0; k < 10; k++) lcand[tid * 10 + k] = top[k];
    __syncthreads();

    for (int pass = 0; pass < 10; pass++) {
        U64 bv = 0; int bp = 0;
        for (int i = tid; i < 2560; i += 256) {
            U64 xv = lcand[i];
            if (xv > bv) { bv = xv; bp = i; }
        }
        rv[tid] = bv; rp[tid] = bp;
        __syncthreads();
        for (int off = 128; off > 0; off >>= 1) {
            if (tid < off) {
                if (rv[tid + off] > rv[tid]) { rv[tid] = rv[tid + off]; rp[tid] = rp[tid + off]; }
            }
            __syncthreads();
        }
        if (tid == 0) {
            cand[((size_t)b * BPB + blk) * 10 + pass] = rv[0];
            lcand[rp[0]] = 0ull;
        }
        __syncthreads();
    }
}

__global__ __launch_bounds__(256) void topk2_kernel(
    const U64* __restrict__ cand, float* __restrict__ pts)
{
    int b = blockIdx.x, tid = threadIdx.x;
    __shared__ U64 lc[BPB * 10];
    __shared__ U64 rv[256];
    __shared__ int rp[256];
    __shared__ int widx[10];
    for (int i = tid; i < BPB * 10; i += 256) lc[i] = cand[(size_t)b * BPB * 10 + i];
    __syncthreads();

    for (int pass = 0; pass < 10; pass++) {
        U64 bv = 0; int bp = 0;
        for (int i = tid; i < BPB * 10; i += 256) {
            U64 xv = lc[i];
            if (xv > bv) { bv = xv; bp = i; }
        }
        rv[tid] = bv; rp[tid] = bp;
        __syncthreads();
        for (int off = 128; off > 0; off >>= 1) {
            if (tid < off) {
                if (rv[tid + off] > rv[tid]) { rv[tid] = rv[tid + off]; rp[tid] = rp[tid + off]; }
            }
            __syncthreads();
        }
        if (tid == 0) { widx[pass] = (int)(IDXM - (u32)(rv[0] & 0xffffffffu)); lc[rp[0]] = 0ull; }
        __syncthreads();
    }
    if (tid < 10) pts[(size_t)b * GV + widx[tid]] = 1.0f;
}

// ---------------------------------------------------------------------------
extern "C" void kernel_launch(void* const* d_in, const int* in_sizes, int n_in,
                              void* d_out, int out_size, void* d_ws, size_t ws_size,
                              hipStream_t stream)
{
    const float* bnd   = (const float*)d_in[0];
    const float* w1    = (const float*)d_in[1];
    const float* b1    = (const float*)d_in[2];
    const float* w2    = (const float*)d_in[3];
    const float* b2    = (const float*)d_in[4];
    const float* fw1   = (const float*)d_in[5];
    const float* fb1   = (const float*)d_in[6];
    const float* fw2   = (const float*)d_in[7];
    const float* fb2   = (const float*)d_in[8];
    const float* noise = (const float*)d_in[9];

    float* out = (float*)d_out;
    char* ws = (char*)d_ws;

    const size_t xbuf_off = 0;                                 // 8 MB
    const size_t pacc_off = xbuf_off + (size_t)NB * GV * 4;    // 512 KB
    const size_t cand_off = pacc_off + (size_t)NB * 64 * 256 * 4;
    const size_t zbuf_off = cand_off + (size_t)NB * BPB * 10 * 8;

    float* xbuf = (float*)(ws + xbuf_off);
    float* pacc = (float*)(ws + pacc_off);
    U64*   cand = (U64*)(ws + cand_off);
    u16*   zbuf = (u16*)(ws + zbuf_off);                       // 8 x 13.5 MB

    dim3 gA(256, NB);       // (4z x 4y) boxes x 8 batches
    convA_mfma_kernel<<<gA, 256, 0, stream>>>(bnd, w1, b1, w2, zbuf);

    dim3 gB(GV / 256, NB);
    convB_kernel<<<gB, 256, 0, stream>>>(zbuf, (size_t)27 * GV, xbuf, (size_t)GV, b2);

    dim3 gfc(32, 64);
    fc1_kernel<<<gfc, 256, 0, stream>>>(fw1, xbuf, pacc);
    fc_final_kernel<<<1, 256, 0, stream>>>(pacc, fb1, fw2, fb2, out + (size_t)NB * GV);

    zero_pts_kernel<<<(NB * GV / 4) / 256, 256, 0, stream>>>((float4*)out);
    dim3 gt(BPB, NB);
    topk1_kernel<<<gt, 256, 0, stream>>>(bnd, noise, cand);
    topk2_kernel<<<NB, 256, 0, stream>>>(cand, out);
}

// Round 10
// 201.428 us; speedup vs baseline: 1.2899x; 1.1327x over previous
//
#include <hip/hip_runtime.h>
#include <math.h>

#define G 64
#define GV (G*G*G)      // 262144
#define NB 8

typedef unsigned short u16;
typedef unsigned int u32;
typedef unsigned long long U64;
typedef __bf16 bf16x8 __attribute__((ext_vector_type(8)));
typedef float f32x4 __attribute__((ext_vector_type(4)));

union BF8 { u16 s[8]; bf16x8 v; };

__device__ __forceinline__ float bf2f(u16 h) {
    union { u32 u; float f; } c; c.u = ((u32)h) << 16; return c.f;
}
__device__ __forceinline__ u16 f2bf(float f) {
    union { float f; u32 u; } c; c.f = f;
    u32 u = c.u;
    return (u16)((u + 0x7fffu + ((u >> 16) & 1u)) >> 16);   // RNE
}
__device__ __forceinline__ u32 cvt_pk_bf16(float lo, float hi) {
    u32 r;
    asm volatile("v_cvt_pk_bf16_f32 %0, %1, %2" : "=v"(r) : "v"(lo), "v"(hi));
    return r;
}

#define YSTRIDE 36   // u32 per voxel row; b128-aligned, 2-way banks

// ---------------------------------------------------------------------------
// convA via MFMA, bf16 weights (headroom verified R9: prob err << 1.02):
//   GEMM1: Y^T[64c x 16v] = W1[64c x 32k] @ X^T[32k x 16v]  (+exact f32 bias)
//          -> relu -> bf16 -> per-wave LDS tile (4 x ds_write_b64)
//   GEMM2: Z^T[32t x 16v] = W2 @ Yh  (2 x ds_read_b128)     -> z bf16
// 8 MFMA / 16-voxel tile. 1-deep pipeline, per-wave double buffer.
// Block: 256 thr = 4 waves, box 4z x 4y x 64x; 16 tiles/wave.
// ---------------------------------------------------------------------------
__global__ __launch_bounds__(256) void convA_mfma_kernel(
    const float* __restrict__ bnd,
    const float* __restrict__ w1, const float* __restrict__ b1,
    const float* __restrict__ w2,
    u16* __restrict__ zbuf)
{
    int b = blockIdx.y;
    const float* bd = bnd + (size_t)b * GV;
    u16* zb = zbuf + (size_t)b * (27 * (size_t)GV);

    __shared__ __align__(16) u16 halo[2378];     // 6*6*66 + zero slot
    __shared__ __align__(16) u32 shpool[4608];   // weights stage -> Y dbufs

    int tid = threadIdx.x;
    int z0 = (blockIdx.x >> 4) * 4, y0 = (blockIdx.x & 15) * 4;

    // ---- coalesced weight stage into shpool-as-float ----
    {
        float* ldsW = (float*)shpool;
        for (int i = tid; i < 3520; i += 256) {
            float v;
            if (i < 1728)      v = w1[i];
            else if (i < 3456) v = w2[i - 1728];
            else               v = b1[i - 3456];
            ldsW[i] = v;
        }
    }

    // ---- halo fill (bf16 bit patterns 0x3F80 / 0) ----
    for (int i = tid; i < 2378; i += 256) {
        u16 hval = 0;
        if (i < 2376) {
            int hz = i / 396, rem = i - hz * 396;
            int hy = rem / 66, hx = rem - hy * 66;
            int gz = z0 + hz - 1, gy = y0 + hy - 1, gx = hx - 1;
            if (((unsigned)gz < (unsigned)G) & ((unsigned)gy < (unsigned)G) &
                ((unsigned)gx < (unsigned)G)) {
                float f = bd[(gz << 12) + (gy << 6) + gx];
                hval = (f > 0.5f) ? (u16)0x3F80 : (u16)0;
            }
        }
        halo[i] = hval;
    }

    __syncthreads();

    int wv = tid >> 6, lane = tid & 63;
    int g = lane >> 4, lr = lane & 15;

    // ---- fragment build from LDS (bf16 weights; k>=27 zero-padded) ----
    const float* ldsW = (const float*)shpool;
    BF8 w1A[4];                     // GEMM1 A: 4 c-tiles, K=27 pad 32
#pragma unroll
    for (int m = 0; m < 4; m++) {
        int c = 16 * m + lr;
#pragma unroll
        for (int j = 0; j < 8; j++) {
            int kk = 8 * g + j;
            float w = (kk < 27) ? ldsW[c * 27 + kk] : 0.0f;
            w1A[m].s[j] = f2bf(w);
        }
    }
    BF8 w2A[2][2];                  // GEMM2 A: 2 t-tiles x 2 K-steps
#pragma unroll
    for (int m2 = 0; m2 < 2; m2++) {
        int t = 16 * m2 + lr;
#pragma unroll
        for (int ks = 0; ks < 2; ks++)
#pragma unroll
            for (int j = 0; j < 8; j++) {
                int ch = 32 * ks + 8 * g + j;
                float w = (t < 27) ? ldsW[1728 + ch * 27 + t] : 0.0f;
                w2A[m2][ks].s[j] = f2bf(w);
            }
    }
    float bias[4][4];               // b1 for D rows c = 16m+4g+r (exact f32)
#pragma unroll
    for (int m = 0; m < 4; m++)
#pragma unroll
        for (int r = 0; r < 4; r++) bias[m][r] = ldsW[3456 + 16 * m + 4 * g + r];

    // ---- per-lane tap offsets (k>=27: any valid cell; A rows are zero) ----
    int tapoff[8];
#pragma unroll
    for (int j = 0; j < 8; j++) {
        int kk = 8 * g + j;
        int kc = kk < 27 ? kk : 0;
        int dz = kc / 9, ry = kc - dz * 9;
        int dy = ry / 3, dx = ry - dy * 3;
        tapoff[j] = dz * 396 + dy * 66 + dx;
    }

    __syncthreads();    // weights region now dead -> reuse as Y buffers

    u32* myY0 = shpool + wv * (2 * 16 * YSTRIDE);
    u32* myY1 = myY0 + 16 * YSTRIDE;

    // GEMM1 + relu + bf16 pack -> DST via 4 x ds_write_b64
    auto gemm1pack = [&](int IT, u32* DST) {
        int li = IT >> 2, xt = IT & 3;
        int l = wv * 4 + li;
        int lineoff = ((l >> 2) * 6 + (l & 3)) * 66 + lr + xt * 16;

        BF8 xB;
#pragma unroll
        for (int j = 0; j < 8; j++)
            xB.s[j] = halo[lineoff + tapoff[j]];

        f32x4 yac[4];
#pragma unroll
        for (int m = 0; m < 4; m++) {
            f32x4 c0;
            c0[0] = bias[m][0]; c0[1] = bias[m][1];
            c0[2] = bias[m][2]; c0[3] = bias[m][3];
            yac[m] = __builtin_amdgcn_mfma_f32_16x16x32_bf16(
                w1A[m].v, xB.v, c0, 0, 0, 0);
        }

#pragma unroll
        for (int m = 0; m < 4; m++) {
            float a0 = fmaxf(yac[m][0], 0.f), a1 = fmaxf(yac[m][1], 0.f);
            float a2 = fmaxf(yac[m][2], 0.f), a3 = fmaxf(yac[m][3], 0.f);
            u32 h01 = cvt_pk_bf16(a0, a1);
            u32 h23 = cvt_pk_bf16(a2, a3);
            *(U64*)&DST[lr * YSTRIDE + 8 * m + 2 * g] =
                (U64)h01 | ((U64)h23 << 32);
        }
    };

    // GEMM2 + store <- SRC (b128 reads at u32 offset 16ks+4g)
    auto gemm2store = [&](int IT, const u32* SRC) {
        int li = IT >> 2, xt = IT & 3;
        int l = wv * 4 + li;
        int vbase = ((z0 + (l >> 2)) << 12) + ((y0 + (l & 3)) << 6) + xt * 16;

        f32x4 zac[2];
        zac[0] = f32x4{0.f, 0.f, 0.f, 0.f};
        zac[1] = f32x4{0.f, 0.f, 0.f, 0.f};
#pragma unroll
        for (int ks = 0; ks < 2; ks++) {
            bf16x8 yBh = *(const bf16x8*)&SRC[lr * YSTRIDE + 16 * ks + 4 * g];
#pragma unroll
            for (int m2 = 0; m2 < 2; m2++)
                zac[m2] = __builtin_amdgcn_mfma_f32_16x16x32_bf16(
                    w2A[m2][ks].v, yBh, zac[m2], 0, 0, 0);
        }

        int vg = vbase + lr;
#pragma unroll
        for (int m2 = 0; m2 < 2; m2++)
#pragma unroll
            for (int r = 0; r < 4; r++) {
                int t = 16 * m2 + 4 * g + r;
                if (t < 27)
                    zb[(size_t)t * GV + vg] = f2bf(zac[m2][r]);
            }
    };

    // ---- 1-deep pipeline over the 16 tiles ----
    gemm1pack(0, myY0);
    for (int it = 1; it < 16; ++it) {
        u32* cur  = (it & 1) ? myY1 : myY0;
        u32* prev = (it & 1) ? myY0 : myY1;
        gemm1pack(it, cur);
        asm volatile("" ::: "memory");
        gemm2store(it - 1, prev);
    }
    asm volatile("" ::: "memory");
    gemm2store(15, myY1);
}

// ---------------------------------------------------------------------------
// Kernel B: conv2 tap-stencil: x2(v) = relu(b2 + sum_t z_t(v + d_t))
// ---------------------------------------------------------------------------
__global__ __launch_bounds__(256) void convB_kernel(
    const u16* __restrict__ zbuf, size_t z_bs,
    float* __restrict__ xout, size_t x_bs,
    const float* __restrict__ b2)
{
    int b = blockIdx.y;
    const u16* zb = zbuf + (size_t)b * z_bs;
    float* xo = xout + (size_t)b * x_bs;

    int v  = blockIdx.x * 256 + threadIdx.x;
    int zc = v >> 12, yc = (v >> 6) & 63, xc = v & 63;
    float acc = b2[0];
#pragma unroll
    for (int dz = -1; dz <= 1; dz++)
#pragma unroll
    for (int dy = -1; dy <= 1; dy++)
#pragma unroll
    for (int dx = -1; dx <= 1; dx++) {
        int t = (dz + 1) * 9 + (dy + 1) * 3 + (dx + 1);
        int zz = zc + dz, yy = yc + dy, xx = xc + dx;
        bool ok = ((unsigned)zz < (unsigned)G) & ((unsigned)yy < (unsigned)G) &
                  ((unsigned)xx < (unsigned)G);
        if (ok) acc += bf2f(zb[(size_t)t * GV + (zz << 12) + (yy << 6) + xx]);
    }
    xo[v] = fmaxf(acc, 0.0f);
}

// ---------------------------------------------------------------------------
// fc1: block (jt, vc) handles 8 rows j0..j0+7 x 4096-v chunk, all 8 batches.
// W stream is use-once -> nontemporal loads via clang-native f32x4.
// ---------------------------------------------------------------------------
__global__ __launch_bounds__(256) void fc1_kernel(
    const float* __restrict__ W, const float* __restrict__ x,
    float* __restrict__ pacc)
{
    int jt = blockIdx.x;            // 0..31
    int vc = blockIdx.y;            // 0..63
    int tid = threadIdx.x;
    int j0 = jt * 8;
    size_t v0 = (size_t)vc * 4096;

    const f32x4* Wp[8];
#pragma unroll
    for (int jj = 0; jj < 8; jj++)
        Wp[jj] = reinterpret_cast<const f32x4*>(W + (size_t)(j0 + jj) * GV + v0);
    const f32x4* Xp[NB];
#pragma unroll
    for (int b = 0; b < NB; b++)
        Xp[b] = reinterpret_cast<const f32x4*>(x + (size_t)b * GV + v0);

    float acc[8][NB];
#pragma unroll
    for (int jj = 0; jj < 8; jj++)
#pragma unroll
        for (int b = 0; b < NB; b++) acc[jj][b] = 0.0f;

    for (int i = 0; i < 4; i++) {
        int e = i * 256 + tid;
        f32x4 wvv[8];
#pragma unroll
        for (int jj = 0; jj < 8; jj++)
            wvv[jj] = __builtin_nontemporal_load(&Wp[jj][e]);
        f32x4 xv[NB];
#pragma unroll
        for (int b = 0; b < NB; b++) xv[b] = Xp[b][e];
#pragma unroll
        for (int b = 0; b < NB; b++) {
#pragma unroll
            for (int jj = 0; jj < 8; jj++) {
                acc[jj][b] = fmaf(wvv[jj][0], xv[b][0], acc[jj][b]);
                acc[jj][b] = fmaf(wvv[jj][1], xv[b][1], acc[jj][b]);
                acc[jj][b] = fmaf(wvv[jj][2], xv[b][2], acc[jj][b]);
                acc[jj][b] = fmaf(wvv[jj][3], xv[b][3], acc[jj][b]);
            }
        }
    }

    __shared__ float sacc[256][36];
    __shared__ float p2[8][40];
#pragma unroll
    for (int pass = 0; pass < 2; pass++) {
        if (pass > 0) __syncthreads();
        float4* row = reinterpret_cast<float4*>(&sacc[tid][0]);
#pragma unroll
        for (int jj = 0; jj < 4; jj++) {
            int js = pass * 4 + jj;
            row[jj * 2 + 0] = make_float4(acc[js][0], acc[js][1], acc[js][2], acc[js][3]);
            row[jj * 2 + 1] = make_float4(acc[js][4], acc[js][5], acc[js][6], acc[js][7]);
        }
        __syncthreads();
        {
            int o = tid & 31, gg = tid >> 5;
            float s = 0.0f;
#pragma unroll
            for (int k = 0; k < 32; k++) s += sacc[gg * 32 + k][o];
            p2[gg][o] = s;
        }
        __syncthreads();
        if (tid < 32) {
            float s = 0.0f;
#pragma unroll
            for (int gg = 0; gg < 8; gg++) s += p2[gg][tid];
            int jj = tid >> 3, b = tid & 7;
            pacc[((size_t)b * 64 + vc) * 256 + (j0 + pass * 4 + jj)] = s;
        }
    }
}

// ---------------------------------------------------------------------------
#define BPB 32
#define IDXM 0x3FFFFu   // GV-1; key low bits = IDXM - idx (smallest idx wins ties)

// topk1 also zeros its slice of the points output (replaces zero_pts kernel)
__global__ __launch_bounds__(256) void topk1_kernel(
    const float* __restrict__ bnd, const float* __restrict__ noise,
    U64* __restrict__ cand, float4* __restrict__ pts_out)
{
    int blk = blockIdx.x;
    int b   = blockIdx.y;
    int tid = threadIdx.x;
    int vbase = blk * (GV / BPB);

    // zero this block's 8192-voxel slice of the points output (float4 x 2048)
    float4* zp = pts_out + ((size_t)b * GV + vbase) / 4;
#pragma unroll
    for (int i = 0; i < 8; i++)
        zp[i * 256 + tid] = make_float4(0.f, 0.f, 0.f, 0.f);

    const float* bd = bnd + (size_t)b * GV + vbase;
    const float* nz = noise + (size_t)b * GV + vbase;

    U64 top[10];
#pragma unroll
    for (int k = 0; k < 10; k++) top[k] = 0ull;

    for (int i = 0; i < (GV / BPB) / 256; i++) {
        int e = i * 256 + tid;
        float bv = bd[e];
        float s  = nz[e];
        U64 p = (bv > 0.5f) ? 0ull
              : ((((U64)__float_as_uint(s)) << 32) |
                 (IDXM - (unsigned)(vbase + e)));
        if (p > top[9]) {
#pragma unroll
            for (int k = 0; k < 10; k++) {
                U64 mx = p > top[k] ? p : top[k];
                U64 mn = p > top[k] ? top[k] : p;
                top[k] = mx; p = mn;
            }
        }
    }

    __shared__ U64 lcand[256 * 10];
    __shared__ U64 rv[256];
    __shared__ int rp[256];
#pragma unroll
    for (int k = 0; k < 10; k++) lcand[tid * 10 + k] = top[k];
    __syncthreads();

    for (int pass = 0; pass < 10; pass++) {
        U64 bv = 0; int bp = 0;
        for (int i = tid; i < 2560; i += 256) {
            U64 xv = lcand[i];
            if (xv > bv) { bv = xv; bp = i; }
        }
        rv[tid] = bv; rp[tid] = bp;
        __syncthreads();
        for (int off = 128; off > 0; off >>= 1) {
            if (tid < off) {
                if (rv[tid + off] > rv[tid]) { rv[tid] = rv[tid + off]; rp[tid] = rp[tid + off]; }
            }
            __syncthreads();
        }
        if (tid == 0) {
            cand[((size_t)b * BPB + blk) * 10 + pass] = rv[0];
            lcand[rp[0]] = 0ull;
        }
        __syncthreads();
    }
}

// blocks 0..7: topk2 per batch; block 8: fc_final (prob output)
__global__ __launch_bounds__(256) void finalize_kernel(
    const U64* __restrict__ cand, float* __restrict__ pts,
    const float* __restrict__ pacc, const float* __restrict__ fc1_b,
    const float* __restrict__ fc2_w, const float* __restrict__ fc2_b,
    float* __restrict__ prob)
{
    int tid = threadIdx.x;

    if (blockIdx.x < 8) {
        int b = blockIdx.x;
        __shared__ U64 lc[BPB * 10];
        __shared__ U64 rv[256];
        __shared__ int rp[256];
        __shared__ int widx[10];
        for (int i = tid; i < BPB * 10; i += 256) lc[i] = cand[(size_t)b * BPB * 10 + i];
        __syncthreads();

        for (int pass = 0; pass < 10; pass++) {
            U64 bv = 0; int bp = 0;
            for (int i = tid; i < BPB * 10; i += 256) {
                U64 xv = lc[i];
                if (xv > bv) { bv = xv; bp = i; }
            }
            rv[tid] = bv; rp[tid] = bp;
            __syncthreads();
            for (int off = 128; off > 0; off >>= 1) {
                if (tid < off) {
                    if (rv[tid + off] > rv[tid]) { rv[tid] = rv[tid + off]; rp[tid] = rp[tid + off]; }
                }
                __syncthreads();
            }
            if (tid == 0) { widx[pass] = (int)(IDXM - (u32)(rv[0] & 0xffffffffu)); lc[rp[0]] = 0ull; }
            __syncthreads();
        }
        if (tid < 10) pts[(size_t)b * GV + widx[tid]] = 1.0f;
    } else {
        int j = tid;
        float h[NB];
#pragma unroll
        for (int b = 0; b < NB; b++) h[b] = 0.0f;
        for (int c = 0; c < 64; c++) {
#pragma unroll
            for (int b = 0; b < NB; b++)
                h[b] += pacc[((size_t)b * 64 + c) * 256 + j];
        }
        float w2j = fc2_w[j];
        float contrib[NB];
#pragma unroll
        for (int b = 0; b < NB; b++)
            contrib[b] = fmaxf(h[b] + fc1_b[j], 0.0f) * w2j;

        int lane = j & 63, wid = j >> 6;
#pragma unroll
        for (int b = 0; b < NB; b++)
#pragma unroll
            for (int off = 32; off > 0; off >>= 1)
                contrib[b] += __shfl_down(contrib[b], off, 64);

        __shared__ float sred[4][NB];
        if (lane == 0) {
#pragma unroll
            for (int b = 0; b < NB; b++) sred[wid][b] = contrib[b];
        }
        __syncthreads();
        if (j < NB) {
            float t = sred[0][j] + sred[1][j] + sred[2][j] + sred[3][j] + fc2_b[0];
            prob[j] = 100.0f / (1.0f + expf(-t));
        }
    }
}

// ---------------------------------------------------------------------------
extern "C" void kernel_launch(void* const* d_in, const int* in_sizes, int n_in,
                              void* d_out, int out_size, void* d_ws, size_t ws_size,
                              hipStream_t stream)
{
    const float* bnd   = (const float*)d_in[0];
    const float* w1    = (const float*)d_in[1];
    const float* b1    = (const float*)d_in[2];
    const float* w2    = (const float*)d_in[3];
    const float* b2    = (const float*)d_in[4];
    const float* fw1   = (const float*)d_in[5];
    const float* fb1   = (const float*)d_in[6];
    const float* fw2   = (const float*)d_in[7];
    const float* fb2   = (const float*)d_in[8];
    const float* noise = (const float*)d_in[9];

    float* out = (float*)d_out;
    char* ws = (char*)d_ws;

    const size_t xbuf_off = 0;                                 // 8 MB
    const size_t pacc_off = xbuf_off + (size_t)NB * GV * 4;    // 512 KB
    const size_t cand_off = pacc_off + (size_t)NB * 64 * 256 * 4;
    const size_t zbuf_off = cand_off + (size_t)NB * BPB * 10 * 8;

    float* xbuf = (float*)(ws + xbuf_off);
    float* pacc = (float*)(ws + pacc_off);
    U64*   cand = (U64*)(ws + cand_off);
    u16*   zbuf = (u16*)(ws + zbuf_off);                       // 8 x 13.5 MB

    dim3 gA(256, NB);       // (4z x 4y) boxes x 8 batches
    convA_mfma_kernel<<<gA, 256, 0, stream>>>(bnd, w1, b1, w2, zbuf);

    dim3 gB(GV / 256, NB);
    convB_kernel<<<gB, 256, 0, stream>>>(zbuf, (size_t)27 * GV, xbuf, (size_t)GV, b2);

    dim3 gfc(32, 64);
    fc1_kernel<<<gfc, 256, 0, stream>>>(fw1, xbuf, pacc);

    dim3 gt(BPB, NB);
    topk1_kernel<<<gt, 256, 0, stream>>>(bnd, noise, cand, (float4*)out);

    finalize_kernel<<<9, 256, 0, stream>>>(cand, out, pacc, fb1, fw2, fb2,
                                           out + (size_t)NB * GV);
}